// Round 8
// baseline (276.640 us; speedup 1.0000x reference)
//
#include <hip/hip_runtime.h>
#include <stdint.h>

// y[m][n] = sum_k x[m][k] * W[k][n] + b[n]
// M=262144, K=128, N=128. 268 MB @ ~6.3 TB/s ~= 43 us floor.
//
// R8: CONTROL ROUND. After 8 experiments (store type, read/write coalescing,
// prefetch, W-staging removal, occupancy 17-72%) the invariant is
// dur = hbm_bytes / 2.42 TB/s with ~zero intercept — structure-independent.
// Per skill rule 10, measure the ceiling with a known-good kernel in THIS
// harness: copy_ctrl does a pure f32x4 grid-stride copy x->y (exact same
// stream shape/bytes), then the real kernel overwrites y correctly.
// rocprof gives copy_ctrl its own dispatch row:
//   ~6 TB/s -> our structure is guilty (dig into MFMA-vs-copy difference)
//   ~2.4 TB/s -> platform wall; 83.5 us dispatch IS the roofline.
// Main kernel = R6 (best known: prep_w once + DMA W->LDS + R4 loop).

typedef __attribute__((ext_vector_type(8))) short bf16x8;   // 8 bf16 = 4 VGPRs
typedef __attribute__((ext_vector_type(4))) float f32x4;    // MFMA C/D

__device__ inline unsigned short f2bf(float f) {
  union { float f; uint32_t u; } v; v.f = f;
  uint32_t r = v.u + 0x7fffu + ((v.u >> 16) & 1u);
  return (unsigned short)(r >> 16);
}

__device__ inline bf16x8 cvt8(f32x4 a, f32x4 b) {
  bf16x8 r;
  r[0] = f2bf(a[0]); r[1] = f2bf(a[1]); r[2] = f2bf(a[2]); r[3] = f2bf(a[3]);
  r[4] = f2bf(b[0]); r[5] = f2bf(b[1]); r[6] = f2bf(b[2]); r[7] = f2bf(b[3]);
  return r;
}

__device__ inline void gload_lds16(const void* g, void* l) {
  __builtin_amdgcn_global_load_lds(
      (const __attribute__((address_space(1))) unsigned int*)g,
      (__attribute__((address_space(3))) unsigned int*)l, 16, 0, 0);
}

// ---- CONTROL: pure f32x4 streaming copy, 134 MB read + 134 MB write.
// Same bytes, same buffers, same harness. y is overwritten afterwards by
// the real kernel, so final output is still correct.
__global__ __launch_bounds__(256) void copy_ctrl(const f32x4* __restrict__ src,
                                                 f32x4* __restrict__ dst) {
  // 262144*128 floats = 8388608 f32x4; 2048x256 threads -> 16 per thread
  size_t i = (size_t)blockIdx.x * 256 + threadIdx.x;
  #pragma unroll 4
  for (; i < 8388608u; i += (size_t)2048 * 256) dst[i] = src[i];
}

// ---- one-time: W (fp32 [128][128]) -> bf16 A-fragment image in workspace.
//   ws[g*8 + j] = f2bf(W[kk*32+qk*8+j][nt*16+lc]),  g = (kk*8+nt)*64 + qk*16+lc
__global__ void prep_w(const float* __restrict__ w,
                       unsigned short* __restrict__ wfrag) {
  int g = blockIdx.x * 256 + threadIdx.x;   // 8 blocks x 256 = 2048 groups
  int fragid = g >> 6;             // kk*8+nt
  int slot   = g & 63;             // qk*16+lc
  int kk = fragid >> 3, nt = fragid & 7;
  int qk = slot >> 4,   lc = slot & 15;
  const float* wp = w + (size_t)(kk * 32 + qk * 8) * 128 + nt * 16 + lc;
  unsigned short tmp[8];
  #pragma unroll
  for (int j = 0; j < 8; ++j) tmp[j] = f2bf(wp[(size_t)j * 128]);
  *(bf16x8*)&wfrag[(size_t)g * 8] = *(const bf16x8*)tmp;
}

__global__ __launch_bounds__(256, 4) void linear_kernel(
    const float* __restrict__ x, const unsigned short* __restrict__ wfrag,
    const float* __restrict__ bias, float* __restrict__ y) {
  __shared__ __align__(16) unsigned short lds_w[128 * 128];  // 32 KB

  const int t = threadIdx.x;
  const int lane = t & 63;
  const int wave = t >> 6;
  const int col  = lane & 15;                  // y-row within 16-row tile
  const int quad = lane >> 4;

  // 256 rows per block: 4 iters x 64 rows (16 rows/wave/iter)
  const size_t row0 = (size_t)blockIdx.x * 256 + wave * 16 + col;
  const float* xp = x + row0 * 128 + quad * 8;

  // ---- issue iter-0 x loads first ----
  f32x4 buf[8];
  #pragma unroll
  for (int kk = 0; kk < 4; ++kk) {
    buf[2 * kk]     = *(const f32x4*)(xp + kk * 32);
    buf[2 * kk + 1] = *(const f32x4*)(xp + kk * 32 + 4);
  }
  __builtin_amdgcn_sched_barrier(0);

  // ---- W fragment image -> LDS: 8 DMA per wave, L2-hot, zero VALU ----
  #pragma unroll
  for (int i = 0; i < 8; ++i) {
    int seg = wave * 8 + i;                       // 1 KB segment id (0..31)
    gload_lds16(wfrag + (size_t)seg * 512 + lane * 8, &lds_w[(size_t)seg * 512]);
  }

  // bias fragment
  f32x4 bfrag[8];
  #pragma unroll
  for (int nt = 0; nt < 8; ++nt)
    bfrag[nt] = *(const f32x4*)(bias + nt * 16 + quad * 4);

  asm volatile("s_waitcnt vmcnt(0)" ::: "memory");  // drain DMA + iter-0 loads
  __syncthreads();                                  // lds_w visible block-wide

  bf16x8 xf[4];
  #pragma unroll
  for (int kk = 0; kk < 4; ++kk) xf[kk] = cvt8(buf[2 * kk], buf[2 * kk + 1]);

  #pragma unroll
  for (int it = 0; it < 4; ++it) {
    if (it < 3) {
      const float* xpn = xp + (size_t)(it + 1) * 64 * 128;
      #pragma unroll
      for (int kk = 0; kk < 4; ++kk) {
        buf[2 * kk]     = *(const f32x4*)(xpn + kk * 32);
        buf[2 * kk + 1] = *(const f32x4*)(xpn + kk * 32 + 4);
      }
    }
    __builtin_amdgcn_sched_barrier(0);

    float* ypi = y + (row0 + (size_t)it * 64) * 128;
    #pragma unroll
    for (int nt = 0; nt < 8; ++nt) {
      f32x4 acc = bfrag[nt];
      #pragma unroll
      for (int kk = 0; kk < 4; ++kk) {
        bf16x8 wf = *(const bf16x8*)&lds_w[((kk * 8 + nt) * 64 + lane) * 8];
        acc = __builtin_amdgcn_mfma_f32_16x16x32_bf16(wf, xf[kk], acc, 0, 0, 0);
      }
      *(f32x4*)(ypi + nt * 16 + quad * 4) = acc;
    }
    __builtin_amdgcn_sched_barrier(0);

    if (it < 3) {
      #pragma unroll
      for (int kk = 0; kk < 4; ++kk) xf[kk] = cvt8(buf[2 * kk], buf[2 * kk + 1]);
    }
  }
}

// ---- fallback (ws unavailable): self-staging ----
__global__ __launch_bounds__(256, 4) void linear_fallback(
    const float* __restrict__ x, const float* __restrict__ w,
    const float* __restrict__ bias, float* __restrict__ y) {
  __shared__ __align__(16) unsigned short lds_w[128 * 128];
  const int t = threadIdx.x;
  const int lane = t & 63, wave = t >> 6;
  const int col = lane & 15, quad = lane >> 4;
  const size_t row0 = (size_t)blockIdx.x * 256 + wave * 16 + col;
  const float* xp = x + row0 * 128 + quad * 8;
  f32x4 buf[8];
  #pragma unroll
  for (int kk = 0; kk < 4; ++kk) {
    buf[2 * kk]     = *(const f32x4*)(xp + kk * 32);
    buf[2 * kk + 1] = *(const f32x4*)(xp + kk * 32 + 4);
  }
  #pragma unroll
  for (int gi = 0; gi < 8; ++gi) {
    int g = t + 256 * gi;
    int fragid = g >> 6, slot = g & 63;
    int kk = fragid >> 3, nt = fragid & 7;
    int qk = slot >> 4, lc = slot & 15;
    const float* wp = w + (size_t)(kk * 32 + qk * 8) * 128 + nt * 16 + lc;
    unsigned short tmp[8];
    #pragma unroll
    for (int j = 0; j < 8; ++j) tmp[j] = f2bf(wp[(size_t)j * 128]);
    *(bf16x8*)&lds_w[(size_t)g * 8] = *(const bf16x8*)tmp;
  }
  f32x4 bfrag[8];
  #pragma unroll
  for (int nt = 0; nt < 8; ++nt)
    bfrag[nt] = *(const f32x4*)(bias + nt * 16 + quad * 4);
  __syncthreads();
  bf16x8 xf[4];
  #pragma unroll
  for (int kk = 0; kk < 4; ++kk) xf[kk] = cvt8(buf[2 * kk], buf[2 * kk + 1]);
  #pragma unroll
  for (int it = 0; it < 4; ++it) {
    if (it < 3) {
      const float* xpn = xp + (size_t)(it + 1) * 64 * 128;
      #pragma unroll
      for (int kk = 0; kk < 4; ++kk) {
        buf[2 * kk]     = *(const f32x4*)(xpn + kk * 32);
        buf[2 * kk + 1] = *(const f32x4*)(xpn + kk * 32 + 4);
      }
    }
    __builtin_amdgcn_sched_barrier(0);
    float* ypi = y + (row0 + (size_t)it * 64) * 128;
    #pragma unroll
    for (int nt = 0; nt < 8; ++nt) {
      f32x4 acc = bfrag[nt];
      #pragma unroll
      for (int kk = 0; kk < 4; ++kk) {
        bf16x8 wf = *(const bf16x8*)&lds_w[((kk * 8 + nt) * 64 + lane) * 8];
        acc = __builtin_amdgcn_mfma_f32_16x16x32_bf16(wf, xf[kk], acc, 0, 0, 0);
      }
      *(f32x4*)(ypi + nt * 16 + quad * 4) = acc;
    }
    __builtin_amdgcn_sched_barrier(0);
    if (it < 3) {
      #pragma unroll
      for (int kk = 0; kk < 4; ++kk) xf[kk] = cvt8(buf[2 * kk], buf[2 * kk + 1]);
    }
  }
}

extern "C" void kernel_launch(void* const* d_in, const int* in_sizes, int n_in,
                              void* d_out, int out_size, void* d_ws, size_t ws_size,
                              hipStream_t stream) {
  const float* x    = (const float*)d_in[0];
  const float* w    = (const float*)d_in[1];
  const float* bias = (const float*)d_in[2];
  float* y = (float*)d_out;

  // CONTROL: pure copy x->y (same stream shape); real kernel overwrites y.
  copy_ctrl<<<2048, 256, 0, stream>>>((const f32x4*)x, (f32x4*)y);

  if (d_ws && ws_size >= 32768) {
    unsigned short* wfrag = (unsigned short*)d_ws;
    prep_w<<<8, 256, 0, stream>>>(w, wfrag);
    linear_kernel<<<1024, 256, 0, stream>>>(x, wfrag, bias, y);
  } else {
    linear_fallback<<<1024, 256, 0, stream>>>(x, w, bias, y);
  }
}